// Round 15
// baseline (175.221 us; speedup 1.0000x reference)
//
#include <hip/hip_runtime.h>
#include <math.h>

// NetVLAD fp32: N=32, D=512, K=64, P=1024
// R14 lesson: atomic tail = serial death. R7-R14 lesson: one DS pipe can't
// carry both operands + staging (2x oversubscribed). This round: operand
// streams split across pipes. VMEM(vmcnt) and DS(lgkmcnt) are independent:
//  - k1a: BOTH operands per-lane from global (line-dense, L1/L2-resident)
//    -> ZERO main-loop LDS, zero barriers. LDS only for the wave tree.
//  - k2a: A from global in quad-major A''[n][pc][q][k] (written free by
//    k1a's epilogue: lane holds p-quads contiguously); x staged in LDS
//    (8 KB/chunk) with XOR-quad swizzle (stored_q = q ^ (row>>2)&7).
//  - s = sum_p a via spart[n][16][k] (R1-proven), summed in k2a epilogue.
// Both GEMMs: 512 thr + (512,2) (only proven no-spill acc[8][.] config),
// grid 512 -> 2 blocks/CU = 4 waves/SIMD.
// ws: A'' 8MB | wt 128KB | spart 128KB | ssqp 128KB = 8.65 MB (<=8.72 proven)

namespace {

constexpr int NI   = 32;
constexpr int DIMC = 512;
constexpr int KCL  = 64;
constexpr int PIXN = 1024;
constexpr float EPSF = 1e-12f;

#define AS1 __attribute__((address_space(1)))
#define AS3 __attribute__((address_space(3)))

__device__ __forceinline__ void glds16(const float* g, float* l) {
  __builtin_amdgcn_global_load_lds((const AS1 void*)g, (AS3 void*)l, 16, 0, 0);
}

// ---------------------------------------------------------------------------
__global__ __launch_bounds__(256) void k0_wt(const float* __restrict__ w,
                                             float* __restrict__ wt) {
  const int i = blockIdx.x * 256 + threadIdx.x;   // 32768, wt[d][k]
  wt[i] = w[(size_t)(i & 63) * DIMC + (i >> 6)];
}

// ---------------------------------------------------------------------------
// k1a: 512 blocks = (n, pg 0..15 [64p]); 512 thr = 8 waves, (512,2).
// Wave w owns d-rows {64ch + 8w + dd}; lane (lk,ld): k=8lk+i, p=pb+8ld+j.
// Per dd: 2 W-quads + 2 x-quads from GLOBAL (line-dense, L1-shared) + 64 FMA.
// No main-loop LDS. Tree (proven macros) -> wave0: softmax -> A''+spart.
// ---------------------------------------------------------------------------
__global__ __launch_bounds__(512, 2) void k1a_logits(
    const float* __restrict__ x, const float* __restrict__ wt,
    const float* __restrict__ conv_b, float* __restrict__ Ad,
    float* __restrict__ spart)
{
  __shared__ float scr[16384];        // tree: 4 slots x 4096 floats

  const int tid = threadIdx.x;
  const int w  = __builtin_amdgcn_readfirstlane(tid >> 6);   // 0..7
  const int l  = tid & 63;
  const int lk = l & 7, ld = l >> 3;
  const int bid = blockIdx.x;
  const int xcd = bid & 7, rest = bid >> 3;   // n -> XCD n%8
  const int n  = xcd + ((rest & 3) << 3);
  const int pg = rest >> 2;                   // 0..15
  const int pb = pg << 6;

  const float* wbase = wt + (size_t)(w << 3) * KCL + (lk << 3);
  const float* xbase = x + ((size_t)n * DIMC + (w << 3)) * PIXN + pb + (ld << 3);

  float acc[8][8];
#pragma unroll
  for (int i = 0; i < 8; ++i)
#pragma unroll
    for (int j = 0; j < 8; ++j) acc[i][j] = 0.0f;

  for (int ch = 0; ch < 8; ++ch) {    // 512 d in chunks of 64; wave: 8 rows
    const float* wr = wbase + (size_t)ch * 64 * KCL;
    const float* xr = xbase + (size_t)ch * 64 * PIXN;
#pragma unroll
    for (int dd = 0; dd < 8; ++dd) {
      const float4 wa = *reinterpret_cast<const float4*>(wr + dd * KCL);
      const float4 wb = *reinterpret_cast<const float4*>(wr + dd * KCL + 4);
      const float4 xa = *reinterpret_cast<const float4*>(xr + (size_t)dd * PIXN);
      const float4 xb = *reinterpret_cast<const float4*>(xr + (size_t)dd * PIXN + 4);
      const float wv[8] = {wa.x, wa.y, wa.z, wa.w, wb.x, wb.y, wb.z, wb.w};
      const float xv[8] = {xa.x, xa.y, xa.z, xa.w, xb.x, xb.y, xb.z, xb.w};
#pragma unroll
      for (int i = 0; i < 8; ++i)
#pragma unroll
        for (int j = 0; j < 8; ++j)
          acc[i][j] = fmaf(wv[i], xv[j], acc[i][j]);
    }
  }

#define TST(RB)                                                              \
  do {                                                                       \
    _Pragma("unroll") for (int i = 0; i < 8; ++i) {                          \
      *reinterpret_cast<float4*>((RB) + ((2 * i) << 8) + (l << 2)) =         \
          make_float4(acc[i][0], acc[i][1], acc[i][2], acc[i][3]);           \
      *reinterpret_cast<float4*>((RB) + ((2 * i + 1) << 8) + (l << 2)) =     \
          make_float4(acc[i][4], acc[i][5], acc[i][6], acc[i][7]);           \
    }                                                                        \
  } while (0)
#define TADD(RB)                                                             \
  do {                                                                       \
    _Pragma("unroll") for (int i = 0; i < 8; ++i) {                          \
      const float4 t0 = *reinterpret_cast<const float4*>(                    \
          (RB) + ((2 * i) << 8) + (l << 2));                                 \
      const float4 t1 = *reinterpret_cast<const float4*>(                    \
          (RB) + ((2 * i + 1) << 8) + (l << 2));                             \
      acc[i][0] += t0.x; acc[i][1] += t0.y; acc[i][2] += t0.z;               \
      acc[i][3] += t0.w; acc[i][4] += t1.x; acc[i][5] += t1.y;               \
      acc[i][6] += t1.z; acc[i][7] += t1.w;                                  \
    }                                                                        \
  } while (0)

  if (w == 4) TST(scr);
  if (w == 5) TST(scr + 4096);
  if (w == 6) TST(scr + 8192);
  if (w == 7) TST(scr + 12288);
  __syncthreads();
  if (w < 4) TADD(scr + w * 4096);
  __syncthreads();
  if (w == 2) TST(scr);
  if (w == 3) TST(scr + 4096);
  __syncthreads();
  if (w < 2) TADD(scr + w * 4096);
  __syncthreads();
  if (w == 1) TST(scr);
  __syncthreads();

  if (w == 0) {
    TADD(scr);                        // full logits, fixed tree order
    const float4 b0 = *reinterpret_cast<const float4*>(conv_b + (lk << 3));
    const float4 b1 = *reinterpret_cast<const float4*>(conv_b + (lk << 3) + 4);
    const float bv[8] = {b0.x, b0.y, b0.z, b0.w, b1.x, b1.y, b1.z, b1.w};
#pragma unroll
    for (int i = 0; i < 8; ++i)
#pragma unroll
      for (int j = 0; j < 8; ++j) acc[i][j] += bv[i];
    float m[8], S[8];
#pragma unroll
    for (int j = 0; j < 8; ++j) {
      m[j] = acc[0][j];
#pragma unroll
      for (int i = 1; i < 8; ++i) m[j] = fmaxf(m[j], acc[i][j]);
      m[j] = fmaxf(m[j], __shfl_xor(m[j], 1, 64));
      m[j] = fmaxf(m[j], __shfl_xor(m[j], 2, 64));
      m[j] = fmaxf(m[j], __shfl_xor(m[j], 4, 64));
      S[j] = 0.0f;
#pragma unroll
      for (int i = 0; i < 8; ++i) {
        acc[i][j] = __expf(acc[i][j] - m[j]);
        S[j] += acc[i][j];
      }
      S[j] += __shfl_xor(S[j], 1, 64);
      S[j] += __shfl_xor(S[j], 2, 64);
      S[j] += __shfl_xor(S[j], 4, 64);
      S[j] = 1.0f / S[j];
    }
    // A''[n][pc][q][k] quad-major: lane holds p-quads contiguously.
    // quad q=2ld <- acc[i][0..3], q=2ld+1 <- acc[i][4..7]; 256 floats per q.
    float* abase = Ad + (((size_t)n * 16 + pg) * 16 + (ld << 1)) * 256 + (lk << 3) * 4;
#pragma unroll
    for (int i = 0; i < 8; ++i) {
      *reinterpret_cast<float4*>(abase + i * 4) =
          make_float4(acc[i][0] * S[0], acc[i][1] * S[1],
                      acc[i][2] * S[2], acc[i][3] * S[3]);
      *reinterpret_cast<float4*>(abase + 256 + i * 4) =
          make_float4(acc[i][4] * S[4], acc[i][5] * S[5],
                      acc[i][6] * S[6], acc[i][7] * S[7]);
    }
    // spart[n][pg][k]: column sums over this block's 64 p (fixed order)
#pragma unroll
    for (int i = 0; i < 8; ++i) {
      float sp = acc[i][0] * S[0] + acc[i][1] * S[1] + acc[i][2] * S[2] +
                 acc[i][3] * S[3] + acc[i][4] * S[4] + acc[i][5] * S[5] +
                 acc[i][6] * S[6] + acc[i][7] * S[7];
      sp += __shfl_xor(sp, 8, 64);
      sp += __shfl_xor(sp, 16, 64);
      sp += __shfl_xor(sp, 32, 64);
      if (ld == 0) spart[((size_t)n * 16 + pg) * KCL + (lk << 3) + i] = sp;
    }
  }
#undef TST
#undef TADD
}

// ---------------------------------------------------------------------------
// k2a: 512 blocks = (n, dt 0..15 [32d]); 512 thr = 8 waves, (512,2).
// Lane (lk,ld): k=8lk+ii, d=32dt+4ld+jd. Wave w: p-quads {2w,2w+1}/chunk.
// A from GLOBAL A'' (quad-contiguous, L2-resident); x chunk [32][64] in LDS
// via glds16, XOR-swizzled (stored_q = q ^ (row>>2)) -> conflict-free b128.
// acc[8][4]; 3-round tree (8 quads); epilogue: s from spart, -s*c, out, ssqp.
// ---------------------------------------------------------------------------
__global__ __launch_bounds__(512, 2) void k2a_vlad(
    const float* __restrict__ x, const float* __restrict__ Ad,
    const float* __restrict__ spart, const float* __restrict__ cent,
    float* __restrict__ out, float* __restrict__ ssqp)
{
  __shared__ float smem[8192];    // xL[2][2048] (16KB) U scr 4x2048 (32KB)
  float* const xL0 = smem;
  float* const scr = smem;

  const int tid = threadIdx.x;
  const int w  = __builtin_amdgcn_readfirstlane(tid >> 6);   // 0..7
  const int l  = tid & 63;
  const int lk = l & 7, ld = l >> 3;
  const int bid = blockIdx.x;
  const int xcd = bid & 7, rest = bid >> 3;
  const int n  = xcd + ((rest & 3) << 3);
  const int dt = rest >> 2;           // 0..15
  const int d0 = dt << 5;             // 32-d tile

  const float* an = Ad + (size_t)n * 16 * 16 * 256;          // A''[n]
  const float* xn = x + ((size_t)n * DIMC + d0) * PIXN;
  // x staging: thread i -> LDS float-offset 4i (linear); row=i>>4, qs=i&15;
  // source logical quad = qs ^ ((row>>2)&7)
  const int srow = tid >> 4, sqs = tid & 15;
  const int sq  = (sqs ^ ((srow >> 2) & 7));
  const float* xsrc = xn + (size_t)srow * PIXN + (sq << 2);

  // prologue: chunk 0
  glds16(xsrc, xL0 + (tid << 2));

  float acc[8][4];
#pragma unroll
  for (int ii = 0; ii < 8; ++ii)
#pragma unroll
    for (int jd = 0; jd < 4; ++jd) acc[ii][jd] = 0.0f;
  __syncthreads();

  for (int ch = 0; ch < 16; ++ch) {   // P in chunks of 64
    const int cur = ch & 1;
    const float* xLc = xL0 + cur * 2048;
    if (ch < 15)
      glds16(xsrc + (ch + 1) * 64, xL0 + (cur ^ 1) * 2048 + (tid << 2));
    const float* ac = an + (size_t)ch * 16 * 256;   // chunk's 16 quads x 256
#pragma unroll
    for (int q = 0; q < 2; ++q) {
      const int pq = (w << 1) + q;
      float4 xf[4];
#pragma unroll
      for (int jd = 0; jd < 4; ++jd)
        xf[jd] = *reinterpret_cast<const float4*>(
            xLc + ((ld << 2) + jd) * 64 + ((pq ^ ld) << 2));
      const float* aq = ac + (size_t)pq * 256 + (lk << 3) * 4;
#pragma unroll
      for (int ii = 0; ii < 8; ++ii) {
        const float4 af = *reinterpret_cast<const float4*>(aq + ii * 4);
#pragma unroll
        for (int jd = 0; jd < 4; ++jd) {
          acc[ii][jd] = fmaf(af.x, xf[jd].x, acc[ii][jd]);
          acc[ii][jd] = fmaf(af.y, xf[jd].y, acc[ii][jd]);
          acc[ii][jd] = fmaf(af.z, xf[jd].z, acc[ii][jd]);
          acc[ii][jd] = fmaf(af.w, xf[jd].w, acc[ii][jd]);
        }
      }
    }
    __syncthreads();
  }

  // 3-round lane-keyed tree: 8 quads/lane, slot stride 2048 floats
#define TST2(RB)                                                             \
  do {                                                                       \
    _Pragma("unroll") for (int ii = 0; ii < 8; ++ii)                         \
      *reinterpret_cast<float4*>((RB) + (ii << 8) + (l << 2)) =              \
          make_float4(acc[ii][0], acc[ii][1], acc[ii][2], acc[ii][3]);       \
  } while (0)
#define TADD2(RB)                                                            \
  do {                                                                       \
    _Pragma("unroll") for (int ii = 0; ii < 8; ++ii) {                       \
      const float4 t0 = *reinterpret_cast<const float4*>(                    \
          (RB) + (ii << 8) + (l << 2));                                      \
      acc[ii][0] += t0.x; acc[ii][1] += t0.y;                                \
      acc[ii][2] += t0.z; acc[ii][3] += t0.w;                                \
    }                                                                        \
  } while (0)

  if (w >= 4) TST2(scr + (w - 4) * 2048);
  __syncthreads();
  if (w < 4) TADD2(scr + w * 2048);
  __syncthreads();
  if (w == 2) TST2(scr);
  if (w == 3) TST2(scr + 2048);
  __syncthreads();
  if (w < 2) TADD2(scr + w * 2048);
  __syncthreads();
  if (w == 1) TST2(scr);
  __syncthreads();

  if (w == 0) {
    TADD2(scr);   // final, deterministic fixed tree
#pragma unroll
    for (int ii = 0; ii < 8; ++ii) {
      const int k = (lk << 3) + ii;
      float s = 0.0f;
#pragma unroll
      for (int pt = 0; pt < 16; ++pt)                  // fixed order
        s += spart[((size_t)n * 16 + pt) * KCL + k];
      const float4 cf = *reinterpret_cast<const float4*>(
          cent + (size_t)k * DIMC + d0 + (ld << 2));
      float r[4];
      r[0] = acc[ii][0] - s * cf.x;
      r[1] = acc[ii][1] - s * cf.y;
      r[2] = acc[ii][2] - s * cf.z;
      r[3] = acc[ii][3] - s * cf.w;
      *reinterpret_cast<float4*>(
          out + ((size_t)n * KCL + k) * DIMC + d0 + (ld << 2)) =
          make_float4(r[0], r[1], r[2], r[3]);
      float q = fmaf(r[0], r[0], fmaf(r[1], r[1], fmaf(r[2], r[2], r[3] * r[3])));
      q += __shfl_xor(q, 8, 64);
      q += __shfl_xor(q, 16, 64);
      q += __shfl_xor(q, 32, 64);
      if (ld == 0) ssqp[((size_t)n * KCL + k) * 16 + dt] = q;
    }
  }
#undef TST2
#undef TADD2
}

// ---------------------------------------------------------------------------
// k2c: 256 blocks = (n, kc 0..7); intra + global norm in place (proven,
// ssqp now has 16 d-tiles per (n,k)).
// ---------------------------------------------------------------------------
__global__ __launch_bounds__(256) void k2c_norm(
    const float* __restrict__ ssqp, float* __restrict__ out)
{
  __shared__ float invs[64];
  __shared__ float gsh;
  const int tid = threadIdx.x;
  const int n  = blockIdx.x >> 3;
  const int kc = blockIdx.x & 7;
  if (tid < 64) {
    float ssq = 0.0f;
#pragma unroll
    for (int dt = 0; dt < 16; ++dt)
      ssq += ssqp[((size_t)n * KCL + tid) * 16 + dt];   // fixed order
    const float inv = 1.0f / fmaxf(sqrtf(ssq), EPSF);
    invs[tid] = inv;
    float rqv = ssq * inv * inv;
#pragma unroll
    for (int off = 32; off > 0; off >>= 1) rqv += __shfl_xor(rqv, off, 64);
    if (tid == 0) gsh = 1.0f / fmaxf(sqrtf(rqv), EPSF);
  }
  __syncthreads();
  const float sc = invs[(kc << 3) + (tid >> 5)] * gsh;
  float* o = out + ((size_t)n * KCL + (kc << 3)) * DIMC + tid * 16;
#pragma unroll
  for (int q = 0; q < 4; ++q) {
    float4 v = *reinterpret_cast<float4*>(o + (q << 2));
    v.x *= sc; v.y *= sc; v.z *= sc; v.w *= sc;
    *reinterpret_cast<float4*>(o + (q << 2)) = v;
  }
}

}  // namespace

extern "C" void kernel_launch(void* const* d_in, const int* in_sizes, int n_in,
                              void* d_out, int out_size, void* d_ws, size_t ws_size,
                              hipStream_t stream) {
  (void)in_sizes; (void)n_in; (void)out_size; (void)ws_size;
  const float* x      = (const float*)d_in[0];
  const float* cent   = (const float*)d_in[1];
  const float* conv_w = (const float*)d_in[2];
  const float* conv_b = (const float*)d_in[3];
  float* out = (float*)d_out;
  float* ws  = (float*)d_ws;

  // ws (floats): A'' 2097152 | wt 32768 | spart 32768 | ssqp 32768 = 8.65 MB
  float* Ad    = ws;
  float* wt    = Ad + (size_t)NI * PIXN * KCL;
  float* spart = wt + 32768;
  float* ssqp  = spart + 32768;

  k0_wt     <<<128, 256, 0, stream>>>(conv_w, wt);
  k1a_logits<<<512, 512, 0, stream>>>(x, wt, conv_b, Ad, spart);
  k2a_vlad  <<<512, 512, 0, stream>>>(x, Ad, spart, cent, out, ssqp);
  k2c_norm  <<<256, 256, 0, stream>>>(ssqp, out);
}